// Round 7
// baseline (196.425 us; speedup 1.0000x reference)
//
#include <hip/hip_runtime.h>
#include <hip/hip_bf16.h>

typedef __hip_bfloat16 bf16;
typedef __attribute__((ext_vector_type(8))) short short8;
typedef __attribute__((ext_vector_type(4))) float floatx4;

// Problem constants: B=4, S=1024, M=8, D=64, H=8, NF=32, HD=512
#define CB 4
#define CS 1024
#define CM 8
#define CD 64
#define CH 8
#define CNF 32
#define CHD 512

#define OB_STRIDE 520    // attn Sc/P/epilogue staging stride (bf16)
#define OS_STRIDE 68     // finalize staging stride (fp32)
#define AT_STRIDE 72     // LDS atom-row stride (shorts): 36 words -> bank spread

__device__ __forceinline__ float b2f(bf16 x) { return __bfloat162float(x); }
__device__ __forceinline__ float us2f(unsigned short u) {
    union { unsigned int i; float f; } v; v.i = ((unsigned int)u) << 16; return v.f;
}
__device__ __forceinline__ floatx4 mfma16(short8 a, short8 b, floatx4 c) {
    return __builtin_amdgcn_mfma_f32_16x16x32_bf16(a, b, c, 0, 0, 0);
}

// Fragment-order layouts: a "chunk" is 512 bf16 = 1KB = one wave transaction;
// chunk lane l = quad*16 + r holds 8 contiguous elements.
//   Fbf  [ntile(n>>4)][half(e>>5)]        : row n=ntile*16+r, e=half*32+quad*8+j
//   qf/kf[bh][kt(s>>4)][half(f>>5)]       : row s=kt*16+r,   f=half*32+quad*8+j
//   vaf  [b][nblk(n>>4)][ks(k>>5)]        : row n=nblk*16+r (n=m*64+e), k=s
//   Cf   [ot(o>>4)][ks(k>>5)]             : row o=ot*16+r,  k=h*64+e (folded WoWv)
//   tmpf [tile(g>>4)][ks(k>>5)]           : row g=tile*16+r, k=h*64+e
//
// ALGEBRA (r6, verified): out_atoms = (P@va) @ C^T with
//   C[o,(h,e)] = sum_d Wo[o,(h,d)] Wv[(h,d),e]  (tiny, computed in prep).

// ---------------------------------------------------------------------------
// Kernel 1 (prep): 144 blocks.  bx<128: RFF freq matrices; bx>=128: C fold.
// ---------------------------------------------------------------------------
__global__ __launch_bounds__(256) void prep(const float* __restrict__ Wq,
                                            const float* __restrict__ Wk,
                                            const float* __restrict__ freqs,
                                            const float* __restrict__ Wo,
                                            const float* __restrict__ Wv,
                                            bf16* __restrict__ Fqb,
                                            bf16* __restrict__ Fkb,
                                            bf16* __restrict__ Cf) {
    int bx = blockIdx.x, t = threadIdx.x;
    if (bx < 128) {
        int which = bx >> 6, h = (bx >> 3) & 7, ec = bx & 7;
        const float* W = which ? Wk : Wq;
        bf16* Fb = which ? Fkb : Fqb;
        int f = t & 31, el = t >> 5;
        int e = ec * 8 + el;
        float acc = 0.f;
        for (int d = 0; d < 64; ++d)
            acc += W[(h * 64 + d) * 64 + e] * freqs[(h * 64 + d) * 32 + f];
        int ntile = h * 2 + (f >> 4);
        int half = e >> 5, quad = (e >> 3) & 3, j = e & 7;
        Fb[(ntile * 2 + half) * 512 + quad * 128 + (f & 15) * 8 + j] = __float2bfloat16(acc);
    } else {
        // C[o,(h,e)] = sum_d Wo[o,(h,d)] * Wv[(h,d),e]; fragment-order store.
        int fid = ((bx - 128) * 256 + t) * 8;     // 8 e-contiguous entries
        int o = fid >> 9, rem = fid & 511, h = rem >> 6, e0 = rem & 63;
        const float* wo = Wo + o * 512 + h * 64;
        float accv[8];
        #pragma unroll
        for (int i = 0; i < 8; ++i) accv[i] = 0.f;
        for (int d = 0; d < 64; ++d) {
            float wod = wo[d];
            const float* wv = Wv + (size_t)(h * 64 + d) * 64 + e0;
            #pragma unroll
            for (int i = 0; i < 8; ++i) accv[i] += wod * wv[i];
        }
        int k = h * 64 + e0;
        int ot = o >> 4, r0 = o & 15, ks = k >> 5, qd = (k >> 3) & 3;
        union { bf16 ob[8]; short8 s8; } pk;
        #pragma unroll
        for (int i = 0; i < 8; ++i) pk.ob[i] = __float2bfloat16(accv[i]);
        *(short8*)(Cf + (ot * 16 + ks) * 512 + qd * 128 + r0 * 8) = pk.s8;
    }
}

// ---------------------------------------------------------------------------
// Kernel 2: blocks 0..1023 = encode (unchanged); 1024..1151 = va transpose
// to fragment-order bf16 (vaf).
// ---------------------------------------------------------------------------
__global__ __launch_bounds__(256) void encvp(const float* __restrict__ qa_in,
                                             const float* __restrict__ ql,
                                             const float* __restrict__ ka_in,
                                             const float* __restrict__ kl,
                                             const bf16* __restrict__ Fqb,
                                             const bf16* __restrict__ Fkb,
                                             bf16* __restrict__ qf,
                                             bf16* __restrict__ kf,
                                             const float* __restrict__ va_in,
                                             bf16* __restrict__ vaf) {
    __shared__ __align__(16) bf16 smem[20480];   // 40KB (encode path only)
    int t = threadIdx.x;
    int w = t >> 6, l = t & 63;
    int quad = l >> 4, r = l & 15;

    if (blockIdx.x < 1024) {
        // ================= encode path (verified, unchanged) ==============
        int blk = blockIdx.x;
        int xbase = blk * 4;             // 4 (b,s) groups
        int b = xbase >> 10, s0 = xbase & 1023;
        float* wgtF = (float*)smem;              // 64 floats = 128 shorts
        bf16* atq = smem + 128;                  // 32*72 = 2304
        bf16* atk = smem + 128 + 2304;           // 2304
        bf16* zL  = smem + 128 + 4608;           // 4096
        int tw = w & 1, nb = (w >> 1) * 8;

        {
            const float* srcq = qa_in + (size_t)(blk * 32) * 64;
            const float* srck = ka_in + (size_t)(blk * 32) * 64;
            #pragma unroll
            for (int j = 0; j < 2; ++j) {        // 512 float4 / 256 thr = 2
                int idx4 = j * 256 + t;
                int flat = idx4 * 4;
                int row = flat >> 6, e = flat & 63;
                float4 vq = ((const float4*)srcq)[idx4];
                float4 vk = ((const float4*)srck)[idx4];
                union { bf16 ob[4]; uint2 u; } pq, pk2;
                pq.ob[0] = __float2bfloat16(vq.x); pq.ob[1] = __float2bfloat16(vq.y);
                pq.ob[2] = __float2bfloat16(vq.z); pq.ob[3] = __float2bfloat16(vq.w);
                pk2.ob[0] = __float2bfloat16(vk.x); pk2.ob[1] = __float2bfloat16(vk.y);
                pk2.ob[2] = __float2bfloat16(vk.z); pk2.ob[3] = __float2bfloat16(vk.w);
                *(uint2*)(atq + row * AT_STRIDE + e) = pq.u;
                *(uint2*)(atk + row * AT_STRIDE + e) = pk2.u;
            }
        }
        if (t < 64) {
            int which = t >> 5, row = t & 31;
            int si = row >> 3, m = row & 7;
            const float* lwp = (which ? kl : ql) + (size_t)(xbase + si) * 8;
            float lw[8]; float mx = -1e30f;
            #pragma unroll
            for (int j = 0; j < 8; ++j) { lw[j] = lwp[j]; mx = fmaxf(mx, lw[j]); }
            float sm = 0.f;
            #pragma unroll
            for (int j = 0; j < 8; ++j) sm += __expf(lw[j] - mx);
            const float rs = 0.17677669529663687f;  // 1/sqrt(32)
            float osc = which ? rs : rs * 0.125f;
            wgtF[which * 32 + row] = __expf(lw[m] - mx) * (osc / sm);
        }
        __syncthreads();

        for (int which = 0; which < 2; ++which) {
            const bf16* atb2 = which ? atk : atq;
            const bf16* Fb = which ? Fkb : Fqb;

            short8 a0 = *(const short8*)(atb2 + (tw * 16 + r) * AT_STRIDE + quad * 8);
            short8 a1 = *(const short8*)(atb2 + (tw * 16 + r) * AT_STRIDE + quad * 8 + 32);

            floatx4 acc[8];
            #pragma unroll
            for (int nt = 0; nt < 8; ++nt) {
                int ntile = nb + nt;
                short8 b0 = *(const short8*)(Fb + (ntile * 2 + 0) * 512 + l * 8);
                short8 b1 = *(const short8*)(Fb + (ntile * 2 + 1) * 512 + l * 8);
                floatx4 c = {0.f, 0.f, 0.f, 0.f};
                c = mfma16(a0, b0, c);
                c = mfma16(a1, b1, c);
                acc[nt] = c;
            }

            float wv[4];
            #pragma unroll
            for (int reg = 0; reg < 4; ++reg)
                wv[reg] = wgtF[which * 32 + tw * 16 + quad * 4 + reg];

            int si = tw * 2 + (quad >> 1);
            int iss = quad & 1;
            #pragma unroll
            for (int nt = 0; nt < 8; ++nt) {
                int n = (nb + nt) * 16 + r;
                int h = n >> 5, f = n & 31;
                float zc = 0.f, zs = 0.f;
                #pragma unroll
                for (int reg = 0; reg < 4; ++reg) {
                    float sv, cv;
                    __sincosf(acc[nt][reg], &sv, &cv);
                    zc += wv[reg] * cv;
                    zs += wv[reg] * sv;
                }
                zc += __shfl_xor(zc, 16);
                zs += __shfl_xor(zs, 16);
                float val = iss ? zs : zc;
                zL[((which * 4 + si) * 8 + h) * 64 + f + 32 * iss] = __float2bfloat16(val);
            }
        }
        __syncthreads();

        #pragma unroll
        for (int rep = 0; rep < 2; ++rep) {
            int idx = rep * 256 + t;
            int row = idx >> 3, c = idx & 7;
            int which = row >> 5, si = (row >> 3) & 3, h = row & 7;
            bf16* enc = which ? kf : qf;
            short8 v = *(const short8*)(zL + row * 64 + c * 8);
            int s = s0 + si;
            int bh = b * 8 + h;
            int kt = s >> 4, half = c >> 2, qd = c & 3;
            *(short8*)(enc + ((size_t)((bh * 64 + kt) * 2 + half)) * 512
                           + (qd * 16 + (s & 15)) * 8) = v;
        }
    } else {
        // ============ va -> fragment-order bf16 (vaf), no MFMA ============
        int vp = blockIdx.x - 1024;          // [0,128)
        int b = vp >> 5, sc = vp & 31;
        const float* src = va_in + ((size_t)(b * 1024 + sc * 32)) * 512;
        #pragma unroll
        for (int rep = 0; rep < 2; ++rep) {
            int nn = rep * 256 + t;          // n = m*64 + e in [0,512)
            int m = nn >> 6, e = nn & 63, nblk = nn >> 4, rr = nn & 15;
            bf16* dchunk = vaf + ((size_t)((b * 32 + nblk) * 32 + sc)) * 512;
            #pragma unroll
            for (int qd = 0; qd < 4; ++qd) {
                union { bf16 ob[8]; short8 s8; } pk;
                #pragma unroll
                for (int j = 0; j < 8; ++j) {
                    int s = qd * 8 + j;
                    pk.ob[j] = __float2bfloat16(src[(size_t)(s * 8 + m) * 64 + e]);
                }
                *(short8*)(dchunk + (qd * 16 + rr) * 8) = pk.s8;
            }
        }
    }
}

// ---------------------------------------------------------------------------
// Kernel 3: attention, 64 q-rows per block, b-affine XCD mapping.
// 512 blocks, 512 thr = 8 waves, LDS ~68KB -> 2 blocks/CU.
// XCD x (= n&7) serves only batch b = x&3, so its L2 holds exactly ONE
// 1MB vaf panel (+ ~1MB kf) -> all V re-reads are L2 hits; V L2 traffic
// halves vs the 32-q version (1GB -> 512MB).  Structure = round-5 verified
// k-halved flash-lite (P1 exp into Sc; P3 accumulate; deferred normalize).
// ---------------------------------------------------------------------------
__global__ __launch_bounds__(512, 4) void attn_kern(const bf16* __restrict__ qf,
                                                    const bf16* __restrict__ kf,
                                                    const bf16* __restrict__ vaf,
                                                    bf16* __restrict__ tmpf) {
    int n = blockIdx.x;
    int xcd = n & 7, j = n >> 3;         // j in [0,64)
    int b = xcd & 3, p = xcd >> 2;
    int h = j >> 3;
    int qb = p * 8 + (j & 7);            // [0,16): 16 q-blocks of 64 rows
    int bh = b * 8 + h;

    __shared__ __align__(16) bf16 Sc[64 * OB_STRIDE];   // 66.6KB (P + epilogue)
    __shared__ float sumW[8 * 64];                      // 2KB
    __shared__ float invL[64];
    int t = threadIdx.x;
    int w = t >> 6, l = t & 63;         // w in [0,8)
    int quad = l >> 4, r = l & 15;
    int k7 = r & 7;

    const bf16* qfb = qf + (size_t)(bh * 128 + qb * 8) * 512 + l * 8;
    const bf16* kfb = kf + (size_t)(bh * 128) * 512 + l * 8;
    const bf16* vbase = vaf + ((size_t)(b * 32 + w * 4) * 32) * 512 + l * 8;

    floatx4 acc[4][4];                   // [qt][nt], accumulated across halves
    #pragma unroll
    for (int qt = 0; qt < 4; ++qt)
        #pragma unroll
        for (int nt = 0; nt < 4; ++nt) acc[qt][nt] = (floatx4){0.f, 0.f, 0.f, 0.f};
    float ps[4] = {0.f, 0.f, 0.f, 0.f};  // row partial sums, q = qt*16 + r

    for (int khalf = 0; khalf < 2; ++khalf) {
        // ---- P1: exp(QK^T) for this k-half.  Q reloaded per half (L2-hot).
        {
            short8 q[8];
            #pragma unroll
            for (int i = 0; i < 8; ++i) q[i] = *(const short8*)(qfb + i * 512);
            short8 kr[4][2];
            #pragma unroll
            for (int d = 0; d < 4; ++d) {
                kr[d][0] = *(const short8*)(kfb + (size_t)(khalf * 32 + w * 4 + d) * 1024);
                kr[d][1] = *(const short8*)(kfb + (size_t)(khalf * 32 + w * 4 + d) * 1024 + 512);
            }
            #pragma unroll
            for (int i = 0; i < 4; ++i) {
                int ktl = w * 4 + i;             // local k-tile in [0,32)
                #pragma unroll
                for (int qt = 0; qt < 4; ++qt) {
                    floatx4 c = {0.f, 0.f, 0.f, 0.f};
                    c = mfma16(kr[i][0], q[2 * qt], c);
                    c = mfma16(kr[i][1], q[2 * qt + 1], c);
                    int g = ktl * 2 + (quad >> 1);
                    int sw = ((g ^ k7) << 3) + (quad & 1) * 4;
                    union { uint2 u; bf16 bb[4]; } pp;
                    #pragma unroll
                    for (int reg = 0; reg < 4; ++reg) {
                        float e = __expf(c[reg]);
                        ps[qt] += e;
                        pp.bb[reg] = __float2bfloat16(e);
                    }
                    *(uint2*)(Sc + (qt * 16 + r) * OB_STRIDE + sw) = pp.u;
                }
            }
        }
        if (khalf == 1) {
            #pragma unroll
            for (int qt = 0; qt < 4; ++qt) {
                ps[qt] += __shfl_xor(ps[qt], 16);
                ps[qt] += __shfl_xor(ps[qt], 32);
            }
            if (l < 16) {
                #pragma unroll
                for (int qt = 0; qt < 4; ++qt) sumW[w * 64 + qt * 16 + r] = ps[qt];
            }
        }
        __syncthreads();
        if (khalf == 1 && t < 64) {
            float s = 0.f;
            #pragma unroll
            for (int w2 = 0; w2 < 8; ++w2) s += sumW[w2 * 64 + t];
            invL[t] = 1.f / s;     // read only after the post-P3 barrier
        }

        // ---- P3 partial: O += P@va over this half's 512 k.  2-deep V ring.
        {
            short8 vr[2][4];
            #pragma unroll
            for (int d = 0; d < 2; ++d)
                #pragma unroll
                for (int nt = 0; nt < 4; ++nt)
                    vr[d][nt] = *(const short8*)(vbase + nt * 16384
                                                 + (khalf * 16 + d) * 512);
            #pragma unroll
            for (int ks = 0; ks < 16; ++ks) {
                short8 pa[4];
                #pragma unroll
                for (int qt = 0; qt < 4; ++qt)
                    pa[qt] = *(const short8*)(Sc + (qt * 16 + r) * OB_STRIDE
                                              + (((ks * 4 + quad) ^ k7) << 3));
                __builtin_amdgcn_s_setprio(1);
                #pragma unroll
                for (int nt = 0; nt < 4; ++nt)
                    #pragma unroll
                    for (int qt = 0; qt < 4; ++qt)
                        acc[qt][nt] = mfma16(pa[qt], vr[ks & 1][nt], acc[qt][nt]);
                __builtin_amdgcn_s_setprio(0);
                if (ks + 2 < 16) {
                    #pragma unroll
                    for (int nt = 0; nt < 4; ++nt)
                        vr[ks & 1][nt] = *(const short8*)(vbase + nt * 16384
                                                          + (khalf * 16 + ks + 2) * 512);
                }
            }
        }
        __syncthreads();   // Sc reads done (safe to overwrite next half)
    }

    // per-lane normalizers: acc[qt] rows are q = qt*16 + quad*4 + reg
    float inv[4][4];
    #pragma unroll
    for (int qt = 0; qt < 4; ++qt)
        #pragma unroll
        for (int reg = 0; reg < 4; ++reg)
            inv[qt][reg] = invL[qt * 16 + quad * 4 + reg];

    // ---- Epilogue: stage with m-rotated columns, store tmpf fragment-order
    bf16* Ob = Sc;
    #pragma unroll
    for (int qt = 0; qt < 4; ++qt)
        #pragma unroll
        for (int nt = 0; nt < 4; ++nt)
            #pragma unroll
            for (int reg = 0; reg < 4; ++reg) {
                int col = w * 64 + nt * 16 + r;
                int m = col >> 6, d = col & 63;
                int colS = m * 64 + ((d + m * 8) & 63);
                Ob[(qt * 16 + quad * 4 + reg) * OB_STRIDE + colS] =
                    __float2bfloat16(acc[qt][nt][reg] * inv[qt][reg]);
            }
    __syncthreads();

    // tmpf chunks: 32 T-tiles x 2 khalf; ks = h*2 + khalf
    #pragma unroll
    for (int i = 0; i < 8; ++i) {
        int ci = i * 8 + w;                 // 0..63
        int lv = t & 63;
        int T = ci >> 1, kh = ci & 1;
        int quadv = lv >> 4, rv = lv & 15;
        int pp = rv >> 3, m = rv & 7;
        int q_local = T * 2 + pp;
        int d0 = kh * 32 + quadv * 8;
        int colS = m * 64 + ((d0 + m * 8) & 63);
        short8 v = *(const short8*)(Ob + q_local * OB_STRIDE + colS);
        int GT = b * 512 + qb * 32 + T;
        *(short8*)(tmpf + ((size_t)(GT * 16 + h * 2 + kh)) * 512 + lv * 8) = v;
    }
}

// ---------------------------------------------------------------------------
// Kernel 4 (MFMA): out_atoms[g, o] = tmpf-row g @ Cf row o (Wv folded in).
// ---------------------------------------------------------------------------
__global__ __launch_bounds__(256) void finalize(const bf16* __restrict__ tmpf,
                                                const bf16* __restrict__ Cf,
                                                const float* __restrict__ Ww,
                                                const float* __restrict__ ql,
                                                float* __restrict__ out) {
    __shared__ __align__(16) float Os[64][OS_STRIDE];   // 17.4 KB
    __shared__ float fs[8][64];
    int t = threadIdx.x;
    int w = t >> 6, l = t & 63;
    int quad = l >> 4, r = l & 15;
    size_t rowbase = (size_t)blockIdx.x * 64;

    floatx4 acc[4];
    #pragma unroll
    for (int nt = 0; nt < 4; ++nt) acc[nt] = (floatx4){0.f, 0.f, 0.f, 0.f};

    const bf16* afrag = tmpf + ((size_t)(blockIdx.x * 4 + w) * 16) * 512 + l * 8;
    const bf16* bfrag = Cf + l * 8;

    for (int ks = 0; ks < 16; ++ks) {
        short8 a = *(const short8*)(afrag + ks * 512);
        #pragma unroll
        for (int nt = 0; nt < 4; ++nt) {
            short8 bb = *(const short8*)(bfrag + (size_t)(nt * 16 + ks) * 512);
            acc[nt] = mfma16(a, bb, acc[nt]);
        }
    }
    #pragma unroll
    for (int nt = 0; nt < 4; ++nt)
        #pragma unroll
        for (int reg = 0; reg < 4; ++reg)
            Os[w * 16 + quad * 4 + reg][nt * 16 + r] = acc[nt][reg];
    __syncthreads();

    #pragma unroll
    for (int i = 0; i < 4; ++i) {
        int ch = i * 256 + t;
        int rr = ch >> 4, c4 = (ch & 15) * 4;
        float4 v = *(const float4*)&Os[rr][c4];
        *(float4*)(out + (rowbase + rr) * 64 + c4) = v;
    }

    {
        int g = t >> 5, oo = (t & 31) * 2;
        float f0 = 0.f, f1 = 0.f;
        #pragma unroll
        for (int m = 0; m < 8; ++m) {
            f0 += Os[g * 8 + m][oo];
            f1 += Os[g * 8 + m][oo + 1];
        }
        fs[g][oo] = f0 * 0.125f;
        fs[g][oo + 1] = f1 * 0.125f;
    }
    __syncthreads();

    if (t < 64) {
        int g = t >> 3, mm = t & 7;
        size_t x = (size_t)blockIdx.x * 8 + g;
        float nl = ql[x * 8 + mm];
        #pragma unroll
        for (int o = 0; o < 64; ++o) nl += fs[g][o] * Ww[mm * 64 + o];
        out[(size_t)CB * CS * CM * CD + x * 8 + mm] = nl;
    }
}

// ---------------------------------------------------------------------------
extern "C" void kernel_launch(void* const* d_in, const int* in_sizes, int n_in,
                              void* d_out, int out_size, void* d_ws, size_t ws_size,
                              hipStream_t stream) {
    const float* q_atoms = (const float*)d_in[0];
    const float* q_logw  = (const float*)d_in[1];
    const float* k_atoms = (const float*)d_in[2];
    const float* k_logw  = (const float*)d_in[3];
    const float* v_atoms = (const float*)d_in[4];
    // d_in[5] = v_logw (unused by the reference)
    const float* Wq = (const float*)d_in[6];
    const float* Wk = (const float*)d_in[7];
    const float* Wv = (const float*)d_in[8];
    const float* Wo = (const float*)d_in[9];
    const float* Ww = (const float*)d_in[10];
    const float* freqs = (const float*)d_in[11];

    // ws layout (all bf16): Fqb[16384] | Fkb[16384] | qf[2097152]
    //   | kf[2097152] | vaf[2097152 (slot 16M)] | tmpf[16777216] | Cf[32768]
    bf16* Fqb = (bf16*)d_ws;
    bf16* Fkb = Fqb + 16384;
    bf16* qf = Fkb + 16384;
    bf16* kf = qf + 2097152;
    bf16* vaf = kf + 2097152;
    bf16* tmpf = vaf + 2097152 * 8;
    bf16* Cf = tmpf + 16777216;
    float* out = (float*)d_out;

    prep<<<144, 256, 0, stream>>>(Wq, Wk, freqs, Wo, Wv, Fqb, Fkb, Cf);
    encvp<<<1152, 256, 0, stream>>>(q_atoms, q_logw, k_atoms, k_logw,
                                    Fqb, Fkb, qf, kf,
                                    v_atoms, vaf);
    attn_kern<<<512, 512, 0, stream>>>(qf, kf, vaf, tmpf);
    finalize<<<CB * CS / 8, 256, 0, stream>>>(tmpf, Cf, Ww, q_logw, out);
}

// Round 8
// 157.753 us; speedup vs baseline: 1.2451x; 1.2451x over previous
//
#include <hip/hip_runtime.h>
#include <hip/hip_bf16.h>

typedef __hip_bfloat16 bf16;
typedef __attribute__((ext_vector_type(8))) short short8;
typedef __attribute__((ext_vector_type(4))) float floatx4;

// Problem constants: B=4, S=1024, M=8, D=64, H=8, NF=32, HD=512
#define CB 4
#define CS 1024
#define CM 8
#define CD 64
#define CH 8
#define CNF 32
#define CHD 512

#define OB_STRIDE 520    // attn epilogue staging stride (bf16)
#define OS_STRIDE 68     // finalize staging stride (fp32)
#define AT_STRIDE 72     // LDS atom-row stride (shorts): 36 words -> bank spread

__device__ __forceinline__ float b2f(bf16 x) { return __bfloat162float(x); }
__device__ __forceinline__ floatx4 mfma16(short8 a, short8 b, floatx4 c) {
    return __builtin_amdgcn_mfma_f32_16x16x32_bf16(a, b, c, 0, 0, 0);
}
// fp8 (OCP e4m3) MFMA: same 16x16x32 shape/rate as bf16, half the bytes.
__device__ __forceinline__ floatx4 mfma8(uint2 a, uint2 b, floatx4 c) {
    union { uint2 u; long l; } ua, ub;
    ua.u = a; ub.u = b;
    return __builtin_amdgcn_mfma_f32_16x16x32_fp8_fp8(ua.l, ub.l, c, 0, 0, 0);
}
__device__ __forceinline__ unsigned int pk4fp8(float a, float b, float c, float d) {
    unsigned int v = __builtin_amdgcn_cvt_pk_fp8_f32(a, b, 0, false);
    return __builtin_amdgcn_cvt_pk_fp8_f32(c, d, v, true);
}

// Fragment-order layouts: a "chunk" is one wave transaction (1KB bf16 / 512B
// fp8); chunk lane l = quad*16 + r holds 8 contiguous elements.
//   Fbf  [ntile(n>>4)][half(e>>5)]        : row n=ntile*16+r, e=half*32+quad*8+j
//   qf/kf[bh][kt(s>>4)][half(f>>5)]       : row s=kt*16+r,   f=half*32+quad*8+j
//   vaf8 [b][nblk(n>>4)][ks(k>>5)] (fp8)  : row n=nblk*16+r (n=m*64+e), k=s
//   Cf   [ot(o>>4)][ks(k>>5)]             : row o=ot*16+r,  k=h*64+e (folded WoWv)
//   tmpf [tile(g>>4)][ks(k>>5)]           : row g=tile*16+r, k=h*64+e
//
// ALGEBRA (r6, verified): out_atoms = (P@va) @ C^T with
//   C[o,(h,e)] = sum_d Wo[o,(h,d)] Wv[(h,d),e]  (tiny, computed in prep).

// ---------------------------------------------------------------------------
// Kernel 1 (prep): 144 blocks.  bx<128: RFF freq matrices; bx>=128: C fold.
// ---------------------------------------------------------------------------
__global__ __launch_bounds__(256) void prep(const float* __restrict__ Wq,
                                            const float* __restrict__ Wk,
                                            const float* __restrict__ freqs,
                                            const float* __restrict__ Wo,
                                            const float* __restrict__ Wv,
                                            bf16* __restrict__ Fqb,
                                            bf16* __restrict__ Fkb,
                                            bf16* __restrict__ Cf) {
    int bx = blockIdx.x, t = threadIdx.x;
    if (bx < 128) {
        int which = bx >> 6, h = (bx >> 3) & 7, ec = bx & 7;
        const float* W = which ? Wk : Wq;
        bf16* Fb = which ? Fkb : Fqb;
        int f = t & 31, el = t >> 5;
        int e = ec * 8 + el;
        float acc = 0.f;
        for (int d = 0; d < 64; ++d)
            acc += W[(h * 64 + d) * 64 + e] * freqs[(h * 64 + d) * 32 + f];
        int ntile = h * 2 + (f >> 4);
        int half = e >> 5, quad = (e >> 3) & 3, j = e & 7;
        Fb[(ntile * 2 + half) * 512 + quad * 128 + (f & 15) * 8 + j] = __float2bfloat16(acc);
    } else {
        // C[o,(h,e)] = sum_d Wo[o,(h,d)] * Wv[(h,d),e]; fragment-order store.
        int fid = ((bx - 128) * 256 + t) * 8;     // 8 e-contiguous entries
        int o = fid >> 9, rem = fid & 511, h = rem >> 6, e0 = rem & 63;
        const float* wo = Wo + o * 512 + h * 64;
        float accv[8];
        #pragma unroll
        for (int i = 0; i < 8; ++i) accv[i] = 0.f;
        for (int d = 0; d < 64; ++d) {
            float wod = wo[d];
            const float* wv = Wv + (size_t)(h * 64 + d) * 64 + e0;
            #pragma unroll
            for (int i = 0; i < 8; ++i) accv[i] += wod * wv[i];
        }
        int k = h * 64 + e0;
        int ot = o >> 4, r0 = o & 15, ks = k >> 5, qd = (k >> 3) & 3;
        union { bf16 ob[8]; short8 s8; } pk;
        #pragma unroll
        for (int i = 0; i < 8; ++i) pk.ob[i] = __float2bfloat16(accv[i]);
        *(short8*)(Cf + (ot * 16 + ks) * 512 + qd * 128 + r0 * 8) = pk.s8;
    }
}

// ---------------------------------------------------------------------------
// Kernel 2: blocks 0..1023 = encode (unchanged); 1024..1151 = va transpose
// to fragment-order FP8 e4m3 (vaf8).
// ---------------------------------------------------------------------------
__global__ __launch_bounds__(256) void encvp(const float* __restrict__ qa_in,
                                             const float* __restrict__ ql,
                                             const float* __restrict__ ka_in,
                                             const float* __restrict__ kl,
                                             const bf16* __restrict__ Fqb,
                                             const bf16* __restrict__ Fkb,
                                             bf16* __restrict__ qf,
                                             bf16* __restrict__ kf,
                                             const float* __restrict__ va_in,
                                             unsigned char* __restrict__ vaf8) {
    __shared__ __align__(16) bf16 smem[20480];   // 40KB (encode path only)
    int t = threadIdx.x;
    int w = t >> 6, l = t & 63;
    int quad = l >> 4, r = l & 15;

    if (blockIdx.x < 1024) {
        // ================= encode path (verified, unchanged) ==============
        int blk = blockIdx.x;
        int xbase = blk * 4;             // 4 (b,s) groups
        int b = xbase >> 10, s0 = xbase & 1023;
        float* wgtF = (float*)smem;              // 64 floats = 128 shorts
        bf16* atq = smem + 128;                  // 32*72 = 2304
        bf16* atk = smem + 128 + 2304;           // 2304
        bf16* zL  = smem + 128 + 4608;           // 4096
        int tw = w & 1, nb = (w >> 1) * 8;

        {
            const float* srcq = qa_in + (size_t)(blk * 32) * 64;
            const float* srck = ka_in + (size_t)(blk * 32) * 64;
            #pragma unroll
            for (int j = 0; j < 2; ++j) {        // 512 float4 / 256 thr = 2
                int idx4 = j * 256 + t;
                int flat = idx4 * 4;
                int row = flat >> 6, e = flat & 63;
                float4 vq = ((const float4*)srcq)[idx4];
                float4 vk = ((const float4*)srck)[idx4];
                union { bf16 ob[4]; uint2 u; } pq, pk2;
                pq.ob[0] = __float2bfloat16(vq.x); pq.ob[1] = __float2bfloat16(vq.y);
                pq.ob[2] = __float2bfloat16(vq.z); pq.ob[3] = __float2bfloat16(vq.w);
                pk2.ob[0] = __float2bfloat16(vk.x); pk2.ob[1] = __float2bfloat16(vk.y);
                pk2.ob[2] = __float2bfloat16(vk.z); pk2.ob[3] = __float2bfloat16(vk.w);
                *(uint2*)(atq + row * AT_STRIDE + e) = pq.u;
                *(uint2*)(atk + row * AT_STRIDE + e) = pk2.u;
            }
        }
        if (t < 64) {
            int which = t >> 5, row = t & 31;
            int si = row >> 3, m = row & 7;
            const float* lwp = (which ? kl : ql) + (size_t)(xbase + si) * 8;
            float lw[8]; float mx = -1e30f;
            #pragma unroll
            for (int j = 0; j < 8; ++j) { lw[j] = lwp[j]; mx = fmaxf(mx, lw[j]); }
            float sm = 0.f;
            #pragma unroll
            for (int j = 0; j < 8; ++j) sm += __expf(lw[j] - mx);
            const float rs = 0.17677669529663687f;  // 1/sqrt(32)
            float osc = which ? rs : rs * 0.125f;
            wgtF[which * 32 + row] = __expf(lw[m] - mx) * (osc / sm);
        }
        __syncthreads();

        for (int which = 0; which < 2; ++which) {
            const bf16* atb2 = which ? atk : atq;
            const bf16* Fb = which ? Fkb : Fqb;

            short8 a0 = *(const short8*)(atb2 + (tw * 16 + r) * AT_STRIDE + quad * 8);
            short8 a1 = *(const short8*)(atb2 + (tw * 16 + r) * AT_STRIDE + quad * 8 + 32);

            floatx4 acc[8];
            #pragma unroll
            for (int nt = 0; nt < 8; ++nt) {
                int ntile = nb + nt;
                short8 b0 = *(const short8*)(Fb + (ntile * 2 + 0) * 512 + l * 8);
                short8 b1 = *(const short8*)(Fb + (ntile * 2 + 1) * 512 + l * 8);
                floatx4 c = {0.f, 0.f, 0.f, 0.f};
                c = mfma16(a0, b0, c);
                c = mfma16(a1, b1, c);
                acc[nt] = c;
            }

            float wv[4];
            #pragma unroll
            for (int reg = 0; reg < 4; ++reg)
                wv[reg] = wgtF[which * 32 + tw * 16 + quad * 4 + reg];

            int si = tw * 2 + (quad >> 1);
            int iss = quad & 1;
            #pragma unroll
            for (int nt = 0; nt < 8; ++nt) {
                int n = (nb + nt) * 16 + r;
                int h = n >> 5, f = n & 31;
                float zc = 0.f, zs = 0.f;
                #pragma unroll
                for (int reg = 0; reg < 4; ++reg) {
                    float sv, cv;
                    __sincosf(acc[nt][reg], &sv, &cv);
                    zc += wv[reg] * cv;
                    zs += wv[reg] * sv;
                }
                zc += __shfl_xor(zc, 16);
                zs += __shfl_xor(zs, 16);
                float val = iss ? zs : zc;
                zL[((which * 4 + si) * 8 + h) * 64 + f + 32 * iss] = __float2bfloat16(val);
            }
        }
        __syncthreads();

        #pragma unroll
        for (int rep = 0; rep < 2; ++rep) {
            int idx = rep * 256 + t;
            int row = idx >> 3, c = idx & 7;
            int which = row >> 5, si = (row >> 3) & 3, h = row & 7;
            bf16* enc = which ? kf : qf;
            short8 v = *(const short8*)(zL + row * 64 + c * 8);
            int s = s0 + si;
            int bh = b * 8 + h;
            int kt = s >> 4, half = c >> 2, qd = c & 3;
            *(short8*)(enc + ((size_t)((bh * 64 + kt) * 2 + half)) * 512
                           + (qd * 16 + (s & 15)) * 8) = v;
        }
    } else {
        // ============ va -> fragment-order fp8 e4m3 (vaf8) ============
        int vp = blockIdx.x - 1024;          // [0,128)
        int b = vp >> 5, sc = vp & 31;
        const float* src = va_in + ((size_t)(b * 1024 + sc * 32)) * 512;
        #pragma unroll
        for (int rep = 0; rep < 2; ++rep) {
            int nn = rep * 256 + t;          // n = m*64 + e in [0,512)
            int m = nn >> 6, e = nn & 63, nblk = nn >> 4, rr = nn & 15;
            unsigned char* dchunk = vaf8 + ((size_t)((b * 32 + nblk) * 32 + sc)) * 512;
            #pragma unroll
            for (int qd = 0; qd < 4; ++qd) {
                float f[8];
                #pragma unroll
                for (int j = 0; j < 8; ++j) {
                    int s = qd * 8 + j;
                    f[j] = src[(size_t)(s * 8 + m) * 64 + e];
                }
                uint2 u;
                u.x = pk4fp8(f[0], f[1], f[2], f[3]);
                u.y = pk4fp8(f[4], f[5], f[6], f[7]);
                *(uint2*)(dchunk + (qd * 16 + rr) * 8) = u;
            }
        }
    }
}

// ---------------------------------------------------------------------------
// Kernel 3: attention (round-6 verified structure), P and V in FP8 e4m3.
// 1024 blocks, 8 waves.  P1: bf16 QK^T + fused exp -> fp8 pack into Sc
// (32KB); P3: fp8 MFMA T += P@va (same K=32 shape/rate as bf16, half the
// L2 bytes and half the LDS);  deferred fp32 normalize in epilogue.
// ---------------------------------------------------------------------------
__global__ __launch_bounds__(512, 4) void attn_kern(const bf16* __restrict__ qf,
                                                    const bf16* __restrict__ kf,
                                                    const unsigned char* __restrict__ vaf8,
                                                    bf16* __restrict__ tmpf) {
    int n = blockIdx.x;
    int bh = (n & 7) + 8 * (n >> 8);
    int qb = (n >> 3) & 31;
    int b = bh >> 3, h = bh & 7;

    // Sc (fp8 P, 32 rows x 1024B = 32KB) unioned with Ob (bf16 epilogue
    // staging, 32 x OB_STRIDE shorts = 33,280B).
    __shared__ __align__(16) unsigned char SMEM[33280];
    __shared__ float sumW[8 * 32];                 // per-wave row partial sums
    __shared__ float invL[32];                     // 1/rowsum
    unsigned char* Sc8 = SMEM;
    int t = threadIdx.x;
    int w = t >> 6, l = t & 63;         // w in [0,8)
    int quad = l >> 4, r = l & 15;
    int k7 = r & 7;

    // ---- Phase 1: QK^T (bf16) + fused exp -> fp8 pack.
    const bf16* qfb = qf + (size_t)(bh * 128 + qb * 4) * 512 + l * 8;
    short8 q0 = *(const short8*)(qfb);
    short8 q1 = *(const short8*)(qfb + 512);
    short8 q2 = *(const short8*)(qfb + 1024);
    short8 q3 = *(const short8*)(qfb + 1536);

    const bf16* kfb = kf + (size_t)(bh * 128) * 512 + l * 8;
    short8 kr[4][2];
    #pragma unroll
    for (int d = 0; d < 4; ++d) {
        kr[d][0] = *(const short8*)(kfb + (size_t)(w * 8 + d) * 1024);
        kr[d][1] = *(const short8*)(kfb + (size_t)(w * 8 + d) * 1024 + 512);
    }

    float ps0 = 0.f, ps1 = 0.f;          // row partial sums (q=r and q=16+r)
    #pragma unroll
    for (int i = 0; i < 8; ++i) {
        short8 k0 = kr[i & 3][0], k1 = kr[i & 3][1];
        if (i + 4 < 8) {
            kr[i & 3][0] = *(const short8*)(kfb + (size_t)(w * 8 + i + 4) * 1024);
            kr[i & 3][1] = *(const short8*)(kfb + (size_t)(w * 8 + i + 4) * 1024 + 512);
        }
        floatx4 c0 = {0.f, 0.f, 0.f, 0.f}, c1 = {0.f, 0.f, 0.f, 0.f};
        c0 = mfma16(k0, q0, c0); c0 = mfma16(k1, q1, c0);
        c1 = mfma16(k0, q2, c1); c1 = mfma16(k1, q3, c1);
        int ktl = w * 8 + i;
        int chunk = ktl * 2 + (quad >> 1);
        int swb = ((chunk ^ k7) << 3) + (quad & 1) * 4;   // BYTE offset
        float e00 = __expf(c0[0]), e01 = __expf(c0[1]);
        float e02 = __expf(c0[2]), e03 = __expf(c0[3]);
        float e10 = __expf(c1[0]), e11 = __expf(c1[1]);
        float e12 = __expf(c1[2]), e13 = __expf(c1[3]);
        ps0 += e00 + e01 + e02 + e03;
        ps1 += e10 + e11 + e12 + e13;
        *(unsigned int*)(Sc8 + r * 1024 + swb) = pk4fp8(e00, e01, e02, e03);
        *(unsigned int*)(Sc8 + (r + 16) * 1024 + swb) = pk4fp8(e10, e11, e12, e13);
    }
    ps0 += __shfl_xor(ps0, 16); ps0 += __shfl_xor(ps0, 32);
    ps1 += __shfl_xor(ps1, 16); ps1 += __shfl_xor(ps1, 32);
    if (l < 16) {
        sumW[w * 32 + r] = ps0;
        sumW[w * 32 + 16 + r] = ps1;
    }
    __syncthreads();

    if (t < 32) {
        float s = 0.f;
        #pragma unroll
        for (int w2 = 0; w2 < 8; ++w2) s += sumW[w2 * 32 + t];
        invL[t] = 1.f / s;
    }
    // no barrier needed: invL is not read until after the post-P3 barrier

    // ---- Phase 3: T += P@va in fp8 (P unnormalized).  4-deep V ring.
    floatx4 acc0[4], acc1[4];
    #pragma unroll
    for (int nt = 0; nt < 4; ++nt) {
        acc0[nt] = (floatx4){0.f, 0.f, 0.f, 0.f};
        acc1[nt] = (floatx4){0.f, 0.f, 0.f, 0.f};
    }
    const unsigned char* vbase = vaf8 + ((size_t)(b * 32 + w * 4) * 32) * 512 + l * 8;
    uint2 vr[4][4];
    #pragma unroll
    for (int d = 0; d < 4; ++d)
        #pragma unroll
        for (int nt = 0; nt < 4; ++nt)
            vr[d][nt] = *(const uint2*)(vbase + nt * 16384 + d * 512);

    #pragma unroll
    for (int ks = 0; ks < 32; ++ks) {
        int pcb = (((ks * 4 + quad) ^ k7) << 3);          // BYTE offset
        uint2 pa0 = *(const uint2*)(Sc8 + r * 1024 + pcb);
        uint2 pa1 = *(const uint2*)(Sc8 + (16 + r) * 1024 + pcb);
        __builtin_amdgcn_s_setprio(1);
        #pragma unroll
        for (int nt = 0; nt < 4; ++nt) {
            acc0[nt] = mfma8(pa0, vr[ks & 3][nt], acc0[nt]);
            acc1[nt] = mfma8(pa1, vr[ks & 3][nt], acc1[nt]);
        }
        __builtin_amdgcn_s_setprio(0);
        if (ks + 4 < 32) {
            #pragma unroll
            for (int nt = 0; nt < 4; ++nt)
                vr[ks & 3][nt] = *(const uint2*)(vbase + nt * 16384 + (ks + 4) * 512);
        }
    }
    __syncthreads();   // all Sc reads done; invL writes ordered; reuse SMEM

    float inv0[4], inv1[4];
    #pragma unroll
    for (int reg = 0; reg < 4; ++reg) {
        inv0[reg] = invL[quad * 4 + reg];
        inv1[reg] = invL[16 + quad * 4 + reg];
    }

    // ---- Epilogue: stage with m-rotated columns, store tmpf fragment-order
    bf16* Ob = (bf16*)SMEM;
    #pragma unroll
    for (int nt = 0; nt < 4; ++nt)
        #pragma unroll
        for (int reg = 0; reg < 4; ++reg) {
            int col = w * 64 + nt * 16 + r;
            int m = col >> 6, d = col & 63;
            int colS = m * 64 + ((d + m * 8) & 63);
            Ob[(quad * 4 + reg) * OB_STRIDE + colS] =
                __float2bfloat16(acc0[nt][reg] * inv0[reg]);
            Ob[(quad * 4 + reg + 16) * OB_STRIDE + colS] =
                __float2bfloat16(acc1[nt][reg] * inv1[reg]);
        }
    __syncthreads();

    // tmpf chunks: 16 T-tiles x 2 khalf; ks = h*2 + khalf
    #pragma unroll
    for (int i = 0; i < 4; ++i) {
        int ci = i * 8 + w;                 // 0..31
        int lv = t & 63;
        int T = ci >> 1, khalf = ci & 1;
        int quadv = lv >> 4, rv = lv & 15;
        int p = rv >> 3, m = rv & 7;
        int q_local = T * 2 + p;
        int d0 = khalf * 32 + quadv * 8;
        int colS = m * 64 + ((d0 + m * 8) & 63);
        short8 v = *(const short8*)(Ob + q_local * OB_STRIDE + colS);
        int GT = b * 512 + qb * 16 + T;
        *(short8*)(tmpf + ((size_t)(GT * 16 + h * 2 + khalf)) * 512 + lv * 8) = v;
    }
}

// ---------------------------------------------------------------------------
// Kernel 4 (MFMA): out_atoms[g, o] = tmpf-row g @ Cf row o (Wv folded in).
// ---------------------------------------------------------------------------
__global__ __launch_bounds__(256) void finalize(const bf16* __restrict__ tmpf,
                                                const bf16* __restrict__ Cf,
                                                const float* __restrict__ Ww,
                                                const float* __restrict__ ql,
                                                float* __restrict__ out) {
    __shared__ __align__(16) float Os[64][OS_STRIDE];   // 17.4 KB
    __shared__ float fs[8][64];
    int t = threadIdx.x;
    int w = t >> 6, l = t & 63;
    int quad = l >> 4, r = l & 15;
    size_t rowbase = (size_t)blockIdx.x * 64;

    floatx4 acc[4];
    #pragma unroll
    for (int nt = 0; nt < 4; ++nt) acc[nt] = (floatx4){0.f, 0.f, 0.f, 0.f};

    const bf16* afrag = tmpf + ((size_t)(blockIdx.x * 4 + w) * 16) * 512 + l * 8;
    const bf16* bfrag = Cf + l * 8;

    for (int ks = 0; ks < 16; ++ks) {
        short8 a = *(const short8*)(afrag + ks * 512);
        #pragma unroll
        for (int nt = 0; nt < 4; ++nt) {
            short8 bb = *(const short8*)(bfrag + (size_t)(nt * 16 + ks) * 512);
            acc[nt] = mfma16(a, bb, acc[nt]);
        }
    }
    #pragma unroll
    for (int nt = 0; nt < 4; ++nt)
        #pragma unroll
        for (int reg = 0; reg < 4; ++reg)
            Os[w * 16 + quad * 4 + reg][nt * 16 + r] = acc[nt][reg];
    __syncthreads();

    #pragma unroll
    for (int i = 0; i < 4; ++i) {
        int ch = i * 256 + t;
        int rr = ch >> 4, c4 = (ch & 15) * 4;
        float4 v = *(const float4*)&Os[rr][c4];
        *(float4*)(out + (rowbase + rr) * 64 + c4) = v;
    }

    {
        int g = t >> 5, oo = (t & 31) * 2;
        float f0 = 0.f, f1 = 0.f;
        #pragma unroll
        for (int m = 0; m < 8; ++m) {
            f0 += Os[g * 8 + m][oo];
            f1 += Os[g * 8 + m][oo + 1];
        }
        fs[g][oo] = f0 * 0.125f;
        fs[g][oo + 1] = f1 * 0.125f;
    }
    __syncthreads();

    if (t < 64) {
        int g = t >> 3, mm = t & 7;
        size_t x = (size_t)blockIdx.x * 8 + g;
        float nl = ql[x * 8 + mm];
        #pragma unroll
        for (int o = 0; o < 64; ++o) nl += fs[g][o] * Ww[mm * 64 + o];
        out[(size_t)CB * CS * CM * CD + x * 8 + mm] = nl;
    }
}

// ---------------------------------------------------------------------------
extern "C" void kernel_launch(void* const* d_in, const int* in_sizes, int n_in,
                              void* d_out, int out_size, void* d_ws, size_t ws_size,
                              hipStream_t stream) {
    const float* q_atoms = (const float*)d_in[0];
    const float* q_logw  = (const float*)d_in[1];
    const float* k_atoms = (const float*)d_in[2];
    const float* k_logw  = (const float*)d_in[3];
    const float* v_atoms = (const float*)d_in[4];
    // d_in[5] = v_logw (unused by the reference)
    const float* Wq = (const float*)d_in[6];
    const float* Wk = (const float*)d_in[7];
    const float* Wv = (const float*)d_in[8];
    const float* Wo = (const float*)d_in[9];
    const float* Ww = (const float*)d_in[10];
    const float* freqs = (const float*)d_in[11];

    // ws layout: Fqb[16384] | Fkb[16384] | qf[2097152] | kf[2097152]
    //   | vaf8 slot | tmpf[16777216] | Cf[32768]   (bf16 units except vaf8)
    bf16* Fqb = (bf16*)d_ws;
    bf16* Fkb = Fqb + 16384;
    bf16* qf = Fkb + 16384;
    bf16* kf = qf + 2097152;
    bf16* vaf_slot = kf + 2097152;
    unsigned char* vaf8 = (unsigned char*)vaf_slot;
    bf16* tmpf = vaf_slot + 2097152 * 8;
    bf16* Cf = tmpf + 16777216;
    float* out = (float*)d_out;

    prep<<<144, 256, 0, stream>>>(Wq, Wk, freqs, Wo, Wv, Fqb, Fkb, Cf);
    encvp<<<1152, 256, 0, stream>>>(q_atoms, q_logw, k_atoms, k_logw,
                                    Fqb, Fkb, qf, kf,
                                    v_atoms, vaf8);
    attn_kern<<<1024, 512, 0, stream>>>(qf, kf, vaf8, tmpf);
    finalize<<<CB * CS / 8, 256, 0, stream>>>(tmpf, Cf, Ww, q_logw, out);
}